// Round 6
// baseline (291.908 us; speedup 1.0000x reference)
//
#include <hip/hip_runtime.h>
#include <hip/hip_cooperative_groups.h>
#include <stdint.h>

namespace cg = cooperative_groups;

// Problem constants (match reference)
#define B_    1024
#define G_    28
#define NB_   2
#define NC_   20
#define KK    4096
#define NTOT  (B_*G_*G_*NB_)       // 1,605,632
#define THRC  3.0f
#define THRN  0.3f
#define SORT_N 8192                // valid-entry capacity
#define NGRP  (B_*(NC_+1))         // 21504 (batch,label) groups
#define GCAP  8                    // per-group member capacity

#define GRID  512
#define BLK   256
#define GSZ   (GRID*BLK)           // 131072 threads

// Workspace layout (bytes)
#define WS_CNT   0                              // int[4]
#define WS_KEYS  256                            // u64[SORT_N]   (65536)
#define WS_SEL   (WS_KEYS + SORT_N*8)           // int[KK]       (16384)
#define WS_BOX   (WS_SEL + KK*4)                // float4[KK]    (65536)
#define WS_GCNT  (WS_BOX + KK*16)               // int[NGRP]     (86016)
#define WS_GMEM  (WS_GCNT + NGRP*4)             // u16[NGRP*GCAP](344064)

typedef unsigned long long u64;
typedef unsigned short u16;

// Single cooperative kernel: all 5 phases separated by grid.sync().
// P0 zero counters | P1 collect (wave-aggregated atomics) | P2 rank-by-count
// + tie-fill | P3 decode/gather | P4 per-group NMS.
__global__ void __launch_bounds__(BLK, 2)
k_mega(const float* __restrict__ boxes, const float* __restrict__ conf,
       const float* __restrict__ clses, float* __restrict__ out,
       char* __restrict__ ws)
{
    cg::grid_group grid = cg::this_grid();
    __shared__ int wsum[4];

    const int tid  = threadIdx.x;
    const int gtid = blockIdx.x * BLK + tid;
    const int lane = tid & 63;

    int*    cnt  = (int*)   (ws + WS_CNT);
    u64*    keys = (u64*)   (ws + WS_KEYS);
    int*    sel  = (int*)   (ws + WS_SEL);
    float4* box4 = (float4*)(ws + WS_BOX);
    int*    gcnt = (int*)   (ws + WS_GCNT);
    u16*    gmem = (u16*)   (ws + WS_GMEM);

    // ---- P0: zero counters ----
    if (gtid < NGRP) gcnt[gtid] = 0;
    if (gtid < 4)    cnt[gtid]  = 0;
    grid.sync();

    // ---- P1: collect valid (conf > 3.0) entries as sortable u64 keys ----
    // key: high 32 = monotone-mapped f32 score, low 32 = ~idx
    // (desc order => score desc, idx asc). Wave-aggregated atomic: one
    // atomicAdd per wave that has any hit (~14% of waves).
    {
        const float4* conf4 = (const float4*)conf;
        for (int t = gtid; t < NTOT / 4; t += GSZ) {   // wave-uniform trip count
            float4 c4 = conf4[t];
            float cc[4] = {c4.x, c4.y, c4.z, c4.w};
            int nh = 0;
            #pragma unroll
            for (int u = 0; u < 4; ++u) nh += (cc[u] > THRC);
            u64 act = __ballot(nh > 0);
            if (act) {
                int incl = nh;
                #pragma unroll
                for (int off = 1; off < 64; off <<= 1) {
                    int v = __shfl_up(incl, off);
                    if (lane >= off) incl += v;
                }
                int tot = __shfl(incl, 63);
                int base = 0;
                if (lane == 0) base = atomicAdd(cnt, tot);
                base = __shfl(base, 0);
                int pos = base + incl - nh;
                int fb = t * 4;
                #pragma unroll
                for (int u = 0; u < 4; ++u) {
                    if (cc[u] > THRC) {
                        if (pos < SORT_N) {
                            unsigned b = __float_as_uint(cc[u]);
                            b = (b & 0x80000000u) ? ~b : (b | 0x80000000u);
                            keys[pos] = ((u64)b << 32) | (u64)(0xFFFFFFFFu - (unsigned)(fb + u));
                        }
                        pos++;
                    }
                }
            }
        }
    }
    grid.sync();

    // ---- P2: rank-by-count (blocks 0..31) + tie-fill (block GRID-1) ----
    // Rank: key i's slot = #{j : key_j > key_i} (keys distinct). All lanes
    // broadcast-read the same key_j -> L1-resident 17.6 KB table, no LDS.
    {
        int Vtot = min(cnt[0], SORT_N);
        int V = min(Vtot, KK);
        if (gtid < Vtot) {
            u64 k0 = keys[gtid];
            int r = 0, j = 0;
            int lim = Vtot & ~7;
            for (; j < lim; j += 8) {
                r += (int)(keys[j+0] > k0) + (int)(keys[j+1] > k0)
                   + (int)(keys[j+2] > k0) + (int)(keys[j+3] > k0)
                   + (int)(keys[j+4] > k0) + (int)(keys[j+5] > k0)
                   + (int)(keys[j+6] > k0) + (int)(keys[j+7] > k0);
            }
            for (; j < Vtot; ++j) r += (int)(keys[j] > k0);
            if (r < KK) sel[r] = (int)(0xFFFFFFFFu - (unsigned)(k0 & 0xFFFFFFFFull));
        }
        if (blockIdx.x == GRID - 1) {
            // tie-fill: first M=K-V invalid indices lie within the first 8192
            // elements (M<=4096, >=4096 invalids there). Thread covers 32 confs.
            int M = KK - V;
            const float4* conf4 = (const float4*)conf;
            unsigned mask = 0;
            int base = tid * 32;
            #pragma unroll
            for (int q = 0; q < 8; ++q) {
                float4 cv = conf4[tid * 8 + q];
                mask |= (unsigned)(!(cv.x > THRC)) << (q * 4 + 0);
                mask |= (unsigned)(!(cv.y > THRC)) << (q * 4 + 1);
                mask |= (unsigned)(!(cv.z > THRC)) << (q * 4 + 2);
                mask |= (unsigned)(!(cv.w > THRC)) << (q * 4 + 3);
            }
            int c = __popc(mask);
            int incl = c;
            #pragma unroll
            for (int off = 1; off < 64; off <<= 1) {
                int v = __shfl_up(incl, off);
                if (lane >= off) incl += v;
            }
            int wid = tid >> 6;
            if (lane == 63) wsum[wid] = incl;
            __syncthreads();                       // block-uniform branch: safe
            int wbase = 0;
            for (int w = 0; w < wid; ++w) wbase += wsum[w];
            int p = wbase + incl - c;              // exclusive prefix of invalids
            unsigned m = mask;
            while (m) {
                int u = __builtin_ctz(m);
                if (p < M) sel[V + p] = base + u;
                p++;
                m &= m - 1;
            }
        }
    }
    grid.sync();

    // ---- P3: decode + gather the 4096 selected detections ----
    {
        int V = min(cnt[0], KK);
        if (gtid < KK) {
            int k = gtid;
            int idx = sel[k];
            int nb = idx & 1;
            int cell = idx >> 1;              // b*784 + gy*28 + gx
            int gx = cell % G_;
            int t  = cell / G_;
            int gy = t % G_;
            int b  = t / G_;
            float4 bv = *(const float4*)(boxes + (size_t)cell * (NB_ * 4) + nb * 4);
            float cx = (bv.x + (float)gx) / (float)G_;
            float cy = (bv.y + (float)gy) / (float)G_;
            float lf = cx - bv.z * 0.5f, tf = cy - bv.w * 0.5f;
            float rf = cx + bv.z * 0.5f, bf = cy + bv.w * 0.5f;
            // argmax over 20 classes, first-max tie-break
            const float4* cp4 = (const float4*)(clses + (size_t)cell * NC_);
            float best = -3.4e38f; int lab = 0;
            #pragma unroll
            for (int q = 0; q < 5; ++q) {
                float4 cv = cp4[q];
                float vv[4] = {cv.x, cv.y, cv.z, cv.w};
                #pragma unroll
                for (int u = 0; u < 4; ++u) {
                    int ci = q * 4 + u;
                    if (vv[u] > best) { best = vv[u]; lab = ci; }
                }
            }
            lab += 1;
            out[k] = (float)b;
            *(float4*)(out + KK + 4*k) = make_float4(lf, tf, rf, bf);
            out[5*KK + k] = (float)lab;
            out[6*KK + k] = conf[idx];
            out[7*KK + k] = 0.0f;             // keep default
            box4[k] = make_float4(lf, tf, rf, bf);
            if (k < V) {
                int g = b * (NC_ + 1) + lab;
                int pos = atomicAdd(&gcnt[g], 1);
                if (pos < GCAP) gmem[g * GCAP + pos] = (u16)k;
            }
        }
    }
    grid.sync();

    // ---- P4: per-group greedy NMS (one thread per (batch,label) group) ----
    // Suppression never crosses groups; within-group order = global rank
    // order, so this is exactly the reference's greedy NMS.
    if (gtid < NGRP) {
        int g = gtid;
        int m = gcnt[g];
        if (m > 0) {
            m = min(m, GCAP);
            u16 r[GCAP];
            for (int i = 0; i < m; ++i) r[i] = gmem[g * GCAP + i];
            for (int i = 1; i < m; ++i) {          // sort by rank (determinism)
                u16 v = r[i]; int j = i - 1;
                while (j >= 0 && r[j] > v) { r[j + 1] = r[j]; --j; }
                r[j + 1] = v;
            }
            if (m == 1) {
                out[7*KK + r[0]] = 1.0f;
            } else {
                float4 bx[GCAP]; float ar[GCAP];
                for (int i = 0; i < m; ++i) {
                    bx[i] = box4[r[i]];
                    ar[i] = fmaxf(bx[i].z - bx[i].x, 0.f) * fmaxf(bx[i].w - bx[i].y, 0.f);
                }
                unsigned keepm = 0;
                for (int i = 0; i < m; ++i) {
                    bool sup = false;
                    for (int j = 0; j < i; ++j) {
                        if ((keepm >> j) & 1u) {
                            float lx = fmaxf(bx[i].x, bx[j].x), ly = fmaxf(bx[i].y, bx[j].y);
                            float rx = fminf(bx[i].z, bx[j].z), ry = fminf(bx[i].w, bx[j].w);
                            float inter = fmaxf(rx - lx, 0.f) * fmaxf(ry - ly, 0.f);
                            float uni = ar[i] + ar[j] - inter;
                            if (inter / fmaxf(uni, 1e-9f) > THRN) sup = true;
                        }
                    }
                    if (!sup) { keepm |= 1u << i; out[7*KK + r[i]] = 1.0f; }
                }
            }
        }
    }
}

extern "C" void kernel_launch(void* const* d_in, const int* in_sizes, int n_in,
                              void* d_out, int out_size, void* d_ws, size_t ws_size,
                              hipStream_t stream) {
    const float* p_boxes = (const float*)d_in[0];
    const float* p_confs = (const float*)d_in[1];
    const float* p_clses = (const float*)d_in[2];
    float* out = (float*)d_out;
    char* ws = (char*)d_ws;

    void* args[] = {(void*)&p_boxes, (void*)&p_confs, (void*)&p_clses,
                    (void*)&out, (void*)&ws};
    hipLaunchCooperativeKernel(reinterpret_cast<const void*>(&k_mega),
                               dim3(GRID), dim3(BLK), args, 0, stream);
}

// Round 7
// 64.164 us; speedup vs baseline: 4.5494x; 4.5494x over previous
//
#include <hip/hip_runtime.h>
#include <stdint.h>

// Problem constants (match reference)
#define B_    1024
#define G_    28
#define NB_   2
#define NC_   20
#define KK    4096
#define NTOT  (B_*G_*G_*NB_)       // 1,605,632
#define THRC  3.0f
#define THRN  0.3f
#define SORT_N 8192                // valid-entry capacity
#define NGRP  (B_*(NC_+1))         // 21504 (batch,label) groups
#define GCAP  8                    // per-group member capacity
#define RB    256                  // threads per rank block
#define NRB2  (SORT_N/RB)          // 32 rank blocks (+1 fill block)

// Workspace layout (bytes)
#define WS_CNT   0                              // int[4]
#define WS_KEYS  256                            // u64[SORT_N]   (65536)
#define WS_SEL   (WS_KEYS + SORT_N*8)           // int[KK]       (16384)
#define WS_BOX   (WS_SEL + KK*4)                // float4[KK]    (65536)
#define WS_GCNT  (WS_BOX + KK*16)               // int[NGRP]     (86016)
#define WS_GMEM  (WS_GCNT + NGRP*4)             // u16[NGRP*GCAP](344064)

typedef unsigned long long u64;
typedef unsigned short u16;

// Collect valid (conf > 3.0) entries as sortable u64 keys (float4-vectorized,
// wave-aggregated atomic), and zero the per-group counters for later kernels.
// key: high 32 = monotone-mapped f32 score, low 32 = ~idx (desc => score desc, idx asc)
__global__ void k_collect(const float4* __restrict__ conf4, u64* __restrict__ keys,
                          int* cnt, int* __restrict__ gcnt) {
    int t = blockIdx.x * blockDim.x + threadIdx.x;      // t < NTOT/4 exactly
    int lane = threadIdx.x & 63;
    if (t < NGRP) gcnt[t] = 0;
    float4 c4 = conf4[t];
    float cc[4] = {c4.x, c4.y, c4.z, c4.w};
    int nh = 0;
    #pragma unroll
    for (int u = 0; u < 4; ++u) nh += (cc[u] > THRC);
    u64 act = __ballot(nh > 0);
    if (act) {                                          // ~29% of waves
        int incl = nh;
        #pragma unroll
        for (int off = 1; off < 64; off <<= 1) {
            int v = __shfl_up(incl, off);
            if (lane >= off) incl += v;
        }
        int tot = __shfl(incl, 63);
        int base = 0;
        if (lane == 0) base = atomicAdd(cnt, tot);
        base = __shfl(base, 0);
        int pos = base + incl - nh;
        int fb = t * 4;
        #pragma unroll
        for (int u = 0; u < 4; ++u) {
            if (cc[u] > THRC) {
                if (pos < SORT_N) {
                    unsigned b = __float_as_uint(cc[u]);
                    b = (b & 0x80000000u) ? ~b : (b | 0x80000000u);
                    keys[pos] = ((u64)b << 32) | (u64)(0xFFFFFFFFu - (unsigned)(fb + u));
                }
                pos++;
            }
        }
    }
}

// Blocks 0..NRB2-1: rank + decode fused. Block stages all keys in LDS; each
// thread computes rank r = #{j : key_j > key_own} (keys distinct => exact
// slot), then immediately decodes its detection and writes ALL outputs for
// slot r (score recovered from the key, no conf re-gather) + gmem push.
// Block NRB2: tie-fill — first M=K-V invalid indices lie in the first 8192
// elements; writes sel[V..KK) (decoded later by k_finish).
__global__ void __launch_bounds__(RB) k_rankdec(const float* __restrict__ boxes,
                                                const float4* __restrict__ conf4,
                                                const float* __restrict__ clses,
                                                const int* __restrict__ cnt,
                                                const u64* __restrict__ keys,
                                                int* __restrict__ sel,
                                                float* __restrict__ out,
                                                float4* __restrict__ box4,
                                                int* __restrict__ gcnt,
                                                u16* __restrict__ gmem) {
    int tid = threadIdx.x;
    int lane = tid & 63;
    if (blockIdx.x == NRB2) {
        // ---- tie-fill ----
        __shared__ int wsum[4];
        int V = min(cnt[0], KK);
        int M = KK - V;
        if (M <= 0) return;                       // uniform
        unsigned mask = 0;
        int base = tid * 32;
        #pragma unroll
        for (int q = 0; q < 8; ++q) {
            float4 cv = conf4[tid * 8 + q];
            mask |= (unsigned)(!(cv.x > THRC)) << (q * 4 + 0);
            mask |= (unsigned)(!(cv.y > THRC)) << (q * 4 + 1);
            mask |= (unsigned)(!(cv.z > THRC)) << (q * 4 + 2);
            mask |= (unsigned)(!(cv.w > THRC)) << (q * 4 + 3);
        }
        int c = __popc(mask);
        int incl = c;
        #pragma unroll
        for (int off = 1; off < 64; off <<= 1) {
            int v = __shfl_up(incl, off);
            if (lane >= off) incl += v;
        }
        int wid = tid >> 6;
        if (lane == 63) wsum[wid] = incl;
        __syncthreads();
        int wbase = 0;
        for (int w = 0; w < wid; ++w) wbase += wsum[w];
        int p = wbase + incl - c;                 // exclusive prefix of invalids
        unsigned m = mask;
        while (m) {
            int u = __builtin_ctz(m);
            if (p < M) sel[V + p] = base + u;
            p++;
            m &= m - 1;
        }
        return;
    }
    // ---- rank + decode blocks ----
    __shared__ u64 sk[SORT_N];                    // 64 KiB
    int Vtot = min(cnt[0], SORT_N);
    if (blockIdx.x * RB >= Vtot) return;          // uniform
    const ulonglong2* keys2 = (const ulonglong2*)keys;
    for (int i = tid; i * 2 < Vtot; i += RB) {
        ulonglong2 kv = keys2[i];
        sk[2 * i]     = kv.x;
        sk[2 * i + 1] = kv.y;
    }
    __syncthreads();
    int t = blockIdx.x * RB + tid;
    if (t >= Vtot) return;
    u64 k0 = sk[t];
    int r = 0, j = 0;
    int lim = Vtot & ~7;
    for (; j < lim; j += 8) {
        r += (int)(sk[j+0] > k0) + (int)(sk[j+1] > k0)
           + (int)(sk[j+2] > k0) + (int)(sk[j+3] > k0)
           + (int)(sk[j+4] > k0) + (int)(sk[j+5] > k0)
           + (int)(sk[j+6] > k0) + (int)(sk[j+7] > k0);
    }
    for (; j < Vtot; ++j) r += (int)(sk[j] > k0);
    if (r >= KK) return;
    // decode
    int idx = (int)(0xFFFFFFFFu - (unsigned)(k0 & 0xFFFFFFFFull));
    int nb = idx & 1;
    int cell = idx >> 1;              // b*784 + gy*28 + gx
    int gx = cell % G_;
    int t2 = cell / G_;
    int gy = t2 % G_;
    int b  = t2 / G_;
    float4 bv = *(const float4*)(boxes + (size_t)cell * (NB_ * 4) + nb * 4);
    float cx = (bv.x + (float)gx) / (float)G_;
    float cy = (bv.y + (float)gy) / (float)G_;
    float lf = cx - bv.z * 0.5f, tf = cy - bv.w * 0.5f;
    float rf = cx + bv.z * 0.5f, bf = cy + bv.w * 0.5f;
    const float4* cp4 = (const float4*)(clses + (size_t)cell * NC_);
    float best = -3.4e38f; int lab = 0;
    #pragma unroll
    for (int q = 0; q < 5; ++q) {
        float4 cv = cp4[q];
        float vv[4] = {cv.x, cv.y, cv.z, cv.w};
        #pragma unroll
        for (int u = 0; u < 4; ++u) {
            int ci = q * 4 + u;
            if (vv[u] > best) { best = vv[u]; lab = ci; }
        }
    }
    lab += 1;
    out[r] = (float)b;
    *(float4*)(out + KK + 4*r) = make_float4(lf, tf, rf, bf);
    out[5*KK + r] = (float)lab;
    out[6*KK + r] = __uint_as_float((unsigned)(k0 >> 32) ^ 0x80000000u);  // conf>3 => positive
    out[7*KK + r] = 0.0f;             // keep default
    box4[r] = make_float4(lf, tf, rf, bf);
    int g = b * (NC_ + 1) + lab;
    int pos = atomicAdd(&gcnt[g], 1);
    if (pos < GCAP) gmem[g * GCAP + pos] = (u16)r;
}

// Threads t in [V,KK): decode tie-fill slots (keep=0, score gathered).
// Threads t < NGRP: per-group greedy NMS — suppression never crosses
// (batch,label) groups and within-group order = global rank order, so this is
// exactly the reference's greedy NMS. Independent work, no ordering needed.
__global__ void k_finish(const float* __restrict__ boxes, const float* __restrict__ conf,
                         const float* __restrict__ clses, const int* __restrict__ cnt,
                         const int* __restrict__ sel, const float4* __restrict__ box4,
                         const int* __restrict__ gcnt, const u16* __restrict__ gmem,
                         float* __restrict__ out) {
    int t = blockIdx.x * blockDim.x + threadIdx.x;
    int V = min(cnt[0], KK);
    if (t < KK && t >= V) {
        int idx = sel[t];
        int nb = idx & 1;
        int cell = idx >> 1;
        int gx = cell % G_;
        int t2 = cell / G_;
        int gy = t2 % G_;
        int b  = t2 / G_;
        float4 bv = *(const float4*)(boxes + (size_t)cell * (NB_ * 4) + nb * 4);
        float cx = (bv.x + (float)gx) / (float)G_;
        float cy = (bv.y + (float)gy) / (float)G_;
        float lf = cx - bv.z * 0.5f, tf = cy - bv.w * 0.5f;
        float rf = cx + bv.z * 0.5f, bf = cy + bv.w * 0.5f;
        const float4* cp4 = (const float4*)(clses + (size_t)cell * NC_);
        float best = -3.4e38f; int lab = 0;
        #pragma unroll
        for (int q = 0; q < 5; ++q) {
            float4 cv = cp4[q];
            float vv[4] = {cv.x, cv.y, cv.z, cv.w};
            #pragma unroll
            for (int u = 0; u < 4; ++u) {
                int ci = q * 4 + u;
                if (vv[u] > best) { best = vv[u]; lab = ci; }
            }
        }
        out[t] = (float)b;
        *(float4*)(out + KK + 4*t) = make_float4(lf, tf, rf, bf);
        out[5*KK + t] = (float)(lab + 1);
        out[6*KK + t] = conf[idx];
        out[7*KK + t] = 0.0f;
    }
    if (t < NGRP) {
        int g = t;
        int m = gcnt[g];
        if (m > 0) {
            m = min(m, GCAP);
            u16 r[GCAP];
            for (int i = 0; i < m; ++i) r[i] = gmem[g * GCAP + i];
            for (int i = 1; i < m; ++i) {          // sort by rank (determinism)
                u16 v = r[i]; int j = i - 1;
                while (j >= 0 && r[j] > v) { r[j + 1] = r[j]; --j; }
                r[j + 1] = v;
            }
            if (m == 1) {
                out[7*KK + r[0]] = 1.0f;
            } else {
                float4 bx[GCAP]; float ar[GCAP];
                for (int i = 0; i < m; ++i) {
                    bx[i] = box4[r[i]];
                    ar[i] = fmaxf(bx[i].z - bx[i].x, 0.f) * fmaxf(bx[i].w - bx[i].y, 0.f);
                }
                unsigned keepm = 0;
                for (int i = 0; i < m; ++i) {
                    bool sup = false;
                    for (int j = 0; j < i; ++j) {
                        if ((keepm >> j) & 1u) {
                            float lx = fmaxf(bx[i].x, bx[j].x), ly = fmaxf(bx[i].y, bx[j].y);
                            float rx = fminf(bx[i].z, bx[j].z), ry = fminf(bx[i].w, bx[j].w);
                            float inter = fmaxf(rx - lx, 0.f) * fmaxf(ry - ly, 0.f);
                            float uni = ar[i] + ar[j] - inter;
                            if (inter / fmaxf(uni, 1e-9f) > THRN) sup = true;
                        }
                    }
                    if (!sup) { keepm |= 1u << i; out[7*KK + r[i]] = 1.0f; }
                }
            }
        }
    }
}

extern "C" void kernel_launch(void* const* d_in, const int* in_sizes, int n_in,
                              void* d_out, int out_size, void* d_ws, size_t ws_size,
                              hipStream_t stream) {
    const float* p_boxes = (const float*)d_in[0];
    const float* p_confs = (const float*)d_in[1];
    const float* p_clses = (const float*)d_in[2];
    float* out = (float*)d_out;
    char* ws = (char*)d_ws;

    int*    cnt  = (int*)   (ws + WS_CNT);
    u64*    keys = (u64*)   (ws + WS_KEYS);
    int*    sel  = (int*)   (ws + WS_SEL);
    float4* box4 = (float4*)(ws + WS_BOX);
    int*    gcnt = (int*)   (ws + WS_GCNT);
    u16*    gmem = (u16*)   (ws + WS_GMEM);

    hipMemsetAsync(cnt, 0, 16, stream);
    k_collect<<<NTOT / 4 / 256, 256, 0, stream>>>((const float4*)p_confs, keys, cnt, gcnt);
    k_rankdec<<<NRB2 + 1, RB, 0, stream>>>(p_boxes, (const float4*)p_confs, p_clses,
                                           cnt, keys, sel, out, box4, gcnt, gmem);
    k_finish <<<(NGRP + 255) / 256, 256, 0, stream>>>(p_boxes, p_confs, p_clses,
                                                      cnt, sel, box4, gcnt, gmem, out);
}